// Round 1
// baseline (18325.778 us; speedup 1.0000x reference)
//
#include <hip/hip_runtime.h>
#include <math.h>

typedef _Float16 half_t;
typedef _Float16 half8 __attribute__((ext_vector_type(8)));
typedef float f32x4 __attribute__((ext_vector_type(4)));

#define B_ 128
#define T_ 256
#define I_ 512
#define H_ 1024

#define GRID_BLOCKS 512
#define BLK_THR 512

// ---------------------------------------------------------------------------
// prep: convert x fp32 -> fp16 (8 elems/thread)
__global__ void k_convert_x(const float* __restrict__ x, half_t* __restrict__ x16, int n8) {
    int i = blockIdx.x * blockDim.x + threadIdx.x;
    if (i >= n8) return;
    const float4* xv = (const float4*)x;
    float4 a = xv[2 * i], b = xv[2 * i + 1];
    half8 o;
    o[0] = (half_t)a.x; o[1] = (half_t)a.y; o[2] = (half_t)a.z; o[3] = (half_t)a.w;
    o[4] = (half_t)b.x; o[5] = (half_t)b.y; o[6] = (half_t)b.z; o[7] = (half_t)b.w;
    ((half8*)x16)[i] = o;
}

// prep: pack W_ih|W_hh (fp32, torch gate order i,f,g,o) into fp16 MFMA
// B-fragment order. Layout: [hgroup(128)][kb(Ktot/32)][ntile(2)][lane(64)][j(8)]
__global__ void k_pack_w(const float* __restrict__ Wih, const float* __restrict__ Whh,
                         half_t* __restrict__ out, int Kx, int Ktot) {
    int idx = blockIdx.x * blockDim.x + threadIdx.x;
    int total = 4096 * Ktot;
    if (idx >= total) return;
    int j = idx & 7;
    int lane = (idx >> 3) & 63;
    int nt = (idx >> 9) & 1;
    int rest = idx >> 10;
    int nkb = Ktot >> 5;
    int kb = rest % nkb;
    int hg = rest / nkb;
    int nl = nt * 16 + (lane & 15);
    int gate = nl >> 3, hoff = nl & 7;
    int row = gate * 1024 + hg * 8 + hoff;
    int k = kb * 32 + (lane >> 4) * 8 + j;
    float v = (k < Kx) ? Wih[(size_t)row * Kx + k] : Whh[(size_t)row * 1024 + (k - Kx)];
    out[idx] = (half_t)v;
}

// prep: bias packed to [hgroup*32 + gate*8 + hoff], b_ih + b_hh summed
__global__ void k_pack_bias(const float* __restrict__ bih, const float* __restrict__ bhh,
                            float* __restrict__ out) {
    int idx = blockIdx.x * blockDim.x + threadIdx.x;
    if (idx >= 4096) return;
    int hg = idx >> 5, c = idx & 31;
    int gate = c >> 3, hoff = c & 7;
    int row = gate * 1024 + hg * 8 + hoff;
    out[idx] = bih[row] + bhh[row];
}

__global__ void k_zero(unsigned int* __restrict__ p, int n) {
    int i = blockIdx.x * blockDim.x + threadIdx.x;
    if (i < n) p[i] = 0u;
}

// ---------------------------------------------------------------------------
// One LSTM timestep for one (hg, mg) unit, executed by one 512-thread block
// (8 waves: w = kh*2+mh, kh in 0..3). Same verified math as the per-step
// kernel, with the K-split reduced from 8-way to 4-way (gacc 32 KB).
template <int KX>
__device__ __forceinline__ void step_body(
    const half_t* __restrict__ Ax, const half_t* __restrict__ hprev,
    const half_t* __restrict__ Wp, const float* __restrict__ biasp,
    float* __restrict__ cst, half_t* __restrict__ hnext,
    half_t* __restrict__ hseq, int t, int write_seq,
    int hg, int mg, float* gacc)
{
    constexpr int KTOT = KX + 1024;
    constexpr int NKB = KTOT >> 5;     // 48 (L0) / 64 (L1)
    constexpr int KB_PER = NKB >> 2;   // 12 / 16 per kh-wave

    int tid = threadIdx.x;
    int m0 = mg * 64;
    int w = tid >> 6, lane = tid & 63;
    int mh = w & 1, kh = w >> 1;       // kh 0..3
    int q = lane >> 4, ml = lane & 15;

    f32x4 acc00 = (f32x4)0.f, acc01 = (f32x4)0.f, acc10 = (f32x4)0.f, acc11 = (f32x4)0.f;

    int rowA0 = m0 + mh * 32 + ml;
    int rowA1 = rowA0 + 16;
    const size_t xrow0 = ((size_t)rowA0 * T_ + t) * KX;
    const size_t xrow1 = ((size_t)rowA1 * T_ + t) * KX;
    const size_t hrow0 = (size_t)rowA0 * H_;
    const size_t hrow1 = (size_t)rowA1 * H_;

    const half8* Wp8 = (const half8*)Wp;
    const size_t wbase = (size_t)hg * NKB * 128;  // half8 units

    int kb0 = kh * KB_PER;
#pragma unroll
    for (int ib = 0; ib < KB_PER; ib++) {
        int kb = kb0 + ib;
        int kg = kb * 32 + q * 8;
        half8 a0, a1;
        if (kg < KX) {
            a0 = *(const half8*)(Ax + xrow0 + kg);
            a1 = *(const half8*)(Ax + xrow1 + kg);
        } else {
            a0 = *(const half8*)(hprev + hrow0 + (kg - KX));
            a1 = *(const half8*)(hprev + hrow1 + (kg - KX));
        }
        half8 b0 = Wp8[wbase + (size_t)kb * 128 + lane];
        half8 b1 = Wp8[wbase + (size_t)kb * 128 + 64 + lane];
        acc00 = __builtin_amdgcn_mfma_f32_16x16x32_f16(a0, b0, acc00, 0, 0, 0);
        acc01 = __builtin_amdgcn_mfma_f32_16x16x32_f16(a0, b1, acc01, 0, 0, 0);
        acc10 = __builtin_amdgcn_mfma_f32_16x16x32_f16(a1, b0, acc10, 0, 0, 0);
        acc11 = __builtin_amdgcn_mfma_f32_16x16x32_f16(a1, b1, acc11, 0, 0, 0);
    }

    // store partials: C/D layout col=lane&15, row=(lane>>4)*4+r  (m89-verified)
#pragma unroll
    for (int mi = 0; mi < 2; mi++) {
#pragma unroll
        for (int ni = 0; ni < 2; ni++) {
            const f32x4& a = mi == 0 ? (ni == 0 ? acc00 : acc01) : (ni == 0 ? acc10 : acc11);
#pragma unroll
            for (int r = 0; r < 4; r++) {
                int m_l = mh * 32 + mi * 16 + q * 4 + r;
                int n_l = ni * 16 + ml;
                int n_s = n_l ^ ((m_l & 3) << 3);  // bank-conflict swizzle
                gacc[(kh * 64 + m_l) * 32 + n_s] = a[r];
            }
        }
    }
    __syncthreads();

    // reduce across kh partials + elementwise; all 512 threads: (m_l, hoff)
    {
        int m_l = tid >> 3, hoff = tid & 7;
        int sw = (m_l & 3) << 3;
        float pi = 0.f, pf = 0.f, pg = 0.f, po = 0.f;
#pragma unroll
        for (int z = 0; z < 4; z++) {
            const float* g = &gacc[(z * 64 + m_l) * 32];
            pi += g[(0 + hoff) ^ sw];
            pf += g[(8 + hoff) ^ sw];
            pg += g[(16 + hoff) ^ sw];
            po += g[(24 + hoff) ^ sw];
        }
        int bb = hg * 32;
        pi += biasp[bb + hoff];
        pf += biasp[bb + 8 + hoff];
        pg += biasp[bb + 16 + hoff];
        po += biasp[bb + 24 + hoff];
        int mgl = m0 + m_l;
        int hidx = hg * 8 + hoff;
        float cold = cst[mgl * H_ + hidx];
        float si = 1.f / (1.f + __expf(-pi));
        float sf = 1.f / (1.f + __expf(-pf));
        float so = 1.f / (1.f + __expf(-po));
        float tg = 1.f - 2.f / (__expf(2.f * pg) + 1.f);
        float cn = sf * cold + si * tg;
        float th = 1.f - 2.f / (__expf(2.f * cn) + 1.f);
        float hn = so * th;
        cst[mgl * H_ + hidx] = cn;
        hnext[mgl * H_ + hidx] = (half_t)hn;
        if (write_seq) hseq[((size_t)mgl * T_ + t) * H_ + hidx] = (half_t)hn;
    }
}

// ---------------------------------------------------------------------------
// Persistent kernel: 512 blocks co-resident (2/CU guaranteed by
// __launch_bounds__(512,4): VGPR<=128 -> 16 waves/CU; LDS 32KB <= 80KB/block).
// Blocks 0..255 = layer0 units, 256..511 = layer1 units pipelined one step
// behind. One hand-rolled device-scope grid barrier per iteration (257 total).
__launch_bounds__(BLK_THR, 4)
__global__ void lstm_persist(const half_t* __restrict__ x16, half_t* __restrict__ h1seq,
                             const half_t* __restrict__ wp0, const half_t* __restrict__ wp1,
                             const float* __restrict__ bias0, const float* __restrict__ bias1,
                             float* __restrict__ c0, float* __restrict__ c1,
                             half_t* __restrict__ h0a, half_t* __restrict__ h0b,
                             half_t* __restrict__ h2a, half_t* __restrict__ h2b,
                             unsigned* __restrict__ bar)
{
    __shared__ float gacc[4 * 64 * 32];  // 32 KB
    int bid = blockIdx.x;
    int layer = bid >> 8;
    int uid = bid & 255;
    int hg = uid & 127, mg = uid >> 7;

    for (int it = 0; it <= T_; ++it) {
        if (layer == 0) {
            if (it < T_) {
                const half_t* hp = (it & 1) ? h0b : h0a;
                half_t* hn = (it & 1) ? h0a : h0b;
                step_body<512>(x16, hp, wp0, bias0, c0, hn, h1seq, it, 1, hg, mg, gacc);
            }
        } else {
            if (it >= 1) {
                int t = it - 1;
                const half_t* hp = (t & 1) ? h2b : h2a;
                half_t* hn = (t & 1) ? h2a : h2b;
                step_body<1024>(h1seq, hp, wp1, bias1, c1, hn, (half_t*)0, t, 0, hg, mg, gacc);
            }
        }
        // ---- grid barrier (epoch counter, agent scope, bounded spin) ----
        __syncthreads();
        if (threadIdx.x == 0) {
            __threadfence();  // release: writeback this XCD's L2 (cross-XCD visibility)
            __hip_atomic_fetch_add(bar, 1u, __ATOMIC_RELAXED, __HIP_MEMORY_SCOPE_AGENT);
            unsigned tgt = (unsigned)(it + 1) * GRID_BLOCKS;
            int guard = 0;
            while (__hip_atomic_load(bar, __ATOMIC_RELAXED, __HIP_MEMORY_SCOPE_AGENT) < tgt) {
                __builtin_amdgcn_s_sleep(4);
                if (++guard > (1 << 15)) break;  // failsafe: visible fail, not a hang
            }
            __threadfence();  // acquire: invalidate caches before reading others' writes
        }
        __syncthreads();
    }
}

// final FC: out[m] = sum_k h[m][k] * Wfc[k] + bfc  (NC=1)
__global__ void k_fc(const half_t* __restrict__ h, const float* __restrict__ Wfc,
                     const float* __restrict__ bfc, float* __restrict__ out) {
    int m = blockIdx.x, lane = threadIdx.x;
    float s = 0.f;
    for (int k = lane; k < H_; k += 64) s += (float)h[m * H_ + k] * Wfc[k];
#pragma unroll
    for (int o = 32; o; o >>= 1) s += __shfl_down(s, o, 64);
    if (lane == 0) out[m] = s + bfc[0];
}

// ---------------------------------------------------------------------------
extern "C" void kernel_launch(void* const* d_in, const int* in_sizes, int n_in,
                              void* d_out, int out_size, void* d_ws, size_t ws_size,
                              hipStream_t stream) {
    const float* x    = (const float*)d_in[0];
    const float* Wih0 = (const float*)d_in[1];
    const float* Whh0 = (const float*)d_in[2];
    const float* bih0 = (const float*)d_in[3];
    const float* bhh0 = (const float*)d_in[4];
    const float* Wih1 = (const float*)d_in[5];
    const float* Whh1 = (const float*)d_in[6];
    const float* bih1 = (const float*)d_in[7];
    const float* bhh1 = (const float*)d_in[8];
    const float* Wfc  = (const float*)d_in[9];
    const float* bfc  = (const float*)d_in[10];
    float* out = (float*)d_out;

    char* ws = (char*)d_ws;
    size_t off = 0;
    auto carve = [&](size_t bytes) { void* p = ws + off; off += (bytes + 255) & ~(size_t)255; return p; };
    half_t* x16    = (half_t*)carve((size_t)B_ * T_ * I_ * 2);        // 33.5 MB
    half_t* h1_all = (half_t*)carve((size_t)B_ * T_ * H_ * 2);        // 67 MB
    half_t* wp0    = (half_t*)carve((size_t)4096 * 1536 * 2);         // 12.6 MB
    half_t* wp1    = (half_t*)carve((size_t)4096 * 2048 * 2);         // 16.8 MB
    float*  bias0  = (float*)carve(4096 * 4);
    float*  bias1  = (float*)carve(4096 * 4);
    // states: h0a,h0b,h2a,h2b (fp16) + c0,c1 (fp32) + barrier counter
    char*   states = (char*)carve(4 * (size_t)B_ * H_ * 2 + 2 * (size_t)B_ * H_ * 4 + 256);
    if (off > ws_size) return;  // ws too small: leave output untouched (visible failure)

    half_t* h0a = (half_t*)states;
    half_t* h0b = h0a + B_ * H_;
    half_t* h2a = h0b + B_ * H_;
    half_t* h2b = h2a + B_ * H_;
    float*  c0  = (float*)(h2b + B_ * H_);
    float*  c1  = c0 + B_ * H_;
    unsigned* bar = (unsigned*)(c1 + B_ * H_);

    // prep
    k_convert_x<<<(B_ * T_ * I_ / 8 + 255) / 256, 256, 0, stream>>>(x, x16, B_ * T_ * I_ / 8);
    k_pack_w<<<(4096 * 1536 + 255) / 256, 256, 0, stream>>>(Wih0, Whh0, wp0, 512, 1536);
    k_pack_w<<<(4096 * 2048 + 255) / 256, 256, 0, stream>>>(Wih1, Whh1, wp1, 1024, 2048);
    k_pack_bias<<<16, 256, 0, stream>>>(bih0, bhh0, bias0);
    k_pack_bias<<<16, 256, 0, stream>>>(bih1, bhh1, bias1);
    // zero h/c state buffers + barrier counter (2 MB + 256 B)
    k_zero<<<2049, 256, 0, stream>>>((unsigned int*)states, 524352);

    // persistent pipelined recurrence: one launch, 257 grid barriers
    lstm_persist<<<dim3(GRID_BLOCKS), dim3(BLK_THR), 0, stream>>>(
        x16, h1_all, wp0, wp1, bias0, bias1, c0, c1, h0a, h0b, h2a, h2b, bar);

    // final h2 state after t=255 lives in h2a (odd t writes h2a)
    k_fc<<<128, 64, 0, stream>>>(h2a, Wfc, bfc, out);
}

// Round 2
// 8299.692 us; speedup vs baseline: 2.2080x; 2.2080x over previous
//
#include <hip/hip_runtime.h>
#include <math.h>

typedef _Float16 half_t;
typedef _Float16 half8 __attribute__((ext_vector_type(8)));
typedef float f32x4 __attribute__((ext_vector_type(4)));
typedef unsigned long long u64;

#define B_ 128
#define T_ 256
#define I_ 512
#define H_ 1024

// ---------------------------------------------------------------------------
// prep: convert x fp32 -> fp16 (8 elems/thread)
__global__ void k_convert_x(const float* __restrict__ x, half_t* __restrict__ x16, int n8) {
    int i = blockIdx.x * blockDim.x + threadIdx.x;
    if (i >= n8) return;
    const float4* xv = (const float4*)x;
    float4 a = xv[2 * i], b = xv[2 * i + 1];
    half8 o;
    o[0] = (half_t)a.x; o[1] = (half_t)a.y; o[2] = (half_t)a.z; o[3] = (half_t)a.w;
    o[4] = (half_t)b.x; o[5] = (half_t)b.y; o[6] = (half_t)b.z; o[7] = (half_t)b.w;
    ((half8*)x16)[i] = o;
}

// prep: pack W_ih|W_hh (fp32, torch gate order i,f,g,o) into fp16 MFMA
// B-fragment order. Layout: [hgroup(128)][kb(Ktot/32)][ntile(2)][lane(64)][j(8)]
__global__ void k_pack_w(const float* __restrict__ Wih, const float* __restrict__ Whh,
                         half_t* __restrict__ out, int Kx, int Ktot) {
    int idx = blockIdx.x * blockDim.x + threadIdx.x;
    int total = 4096 * Ktot;
    if (idx >= total) return;
    int j = idx & 7;
    int lane = (idx >> 3) & 63;
    int nt = (idx >> 9) & 1;
    int rest = idx >> 10;
    int nkb = Ktot >> 5;
    int kb = rest % nkb;
    int hg = rest / nkb;
    int nl = nt * 16 + (lane & 15);
    int gate = nl >> 3, hoff = nl & 7;
    int row = gate * 1024 + hg * 8 + hoff;
    int k = kb * 32 + (lane >> 4) * 8 + j;
    float v = (k < Kx) ? Wih[(size_t)row * Kx + k] : Whh[(size_t)row * 1024 + (k - Kx)];
    out[idx] = (half_t)v;
}

// prep: bias packed to [hgroup*32 + gate*8 + hoff], b_ih + b_hh summed
__global__ void k_pack_bias(const float* __restrict__ bih, const float* __restrict__ bhh,
                            float* __restrict__ out) {
    int idx = blockIdx.x * blockDim.x + threadIdx.x;
    if (idx >= 4096) return;
    int hg = idx >> 5, c = idx & 31;
    int gate = c >> 3, hoff = c & 7;
    int row = gate * 1024 + hg * 8 + hoff;
    out[idx] = bih[row] + bhh[row];
}

__global__ void k_zero(unsigned int* __restrict__ p, int n) {
    int i = blockIdx.x * blockDim.x + threadIdx.x;
    if (i < n) p[i] = 0u;
}

// ---------------------------------------------------------------------------
// system-scope (L2-bypassing, cross-XCD coherent) data movement for h-state
__device__ __forceinline__ u64 sysld64(const half_t* p) {
    return __hip_atomic_load((const u64*)p, __ATOMIC_RELAXED, __HIP_MEMORY_SCOPE_SYSTEM);
}
__device__ __forceinline__ void sysst32(half_t* p, unsigned v) {
    __hip_atomic_store((unsigned*)p, v, __ATOMIC_RELAXED, __HIP_MEMORY_SCOPE_SYSTEM);
}

// sub-barrier helpers: NO cache-invalidating fences (release = waitcnt+wb only)
__device__ __forceinline__ void wait_ge(unsigned* ctr, unsigned tgt) {
    if (threadIdx.x == 0) {
        int gd = 0;
        while (__hip_atomic_load(ctr, __ATOMIC_RELAXED, __HIP_MEMORY_SCOPE_SYSTEM) < tgt) {
            __builtin_amdgcn_s_sleep(2);
            if (++gd > (1 << 16)) break;  // failsafe: visible fail, not a hang
        }
    }
    __syncthreads();
}
__device__ __forceinline__ void signal(unsigned* ctr) {
    __syncthreads();  // compiler drains vmcnt before s_barrier -> stores complete
    if (threadIdx.x == 0)
        __hip_atomic_fetch_add(ctr, 1u, __ATOMIC_RELEASE, __HIP_MEMORY_SCOPE_SYSTEM);
}

// ---------------------------------------------------------------------------
// One LSTM timestep for one (cg, rg) unit. Block = 512 threads = 8 waves,
// wave w owns n-tile w of the block's 128 gate-cols; 16 rows; full-K acc.
// A staged in LDS in 2 K-chunks, XOR-swizzled (byte ^= (row&7)<<4).
template <int KTOT, int KX, bool LAY1>
__device__ void lstm_step_p(const half_t* __restrict__ x16,
                            half_t* h1seqT,            // [t 0..T][row 128][unit 1024]
                            const half_t* h2prev, half_t* h2next,
                            const half_t* __restrict__ Wp,
                            const float* __restrict__ biasp,
                            float* __restrict__ cst,
                            int t, int rg, int cg,
                            char* smA, float* gbuf)
{
    constexpr int NKB    = KTOT >> 5;            // 48 / 64 k-blocks total
    constexpr int KBH    = NKB >> 1;             // 24 / 32 per chunk
    constexpr int U64PR  = KTOT >> 3;            // u64 per row per chunk: 192 / 256
    constexpr int ROUNDS = (16 * U64PR) / 512;   // 6 / 8

    const int tid = threadIdx.x;
    const int w = tid >> 6, lane = tid & 63;
    const int q = lane >> 4, ml = lane & 15;
    const int hg = cg * 4 + (w >> 1);
    const int nt = w & 1;
    const int r0 = rg * 16;

    const half8* Wp8 = (const half8*)Wp;
    const size_t wbase = ((size_t)hg * NKB) * 128 + (size_t)nt * 64 + lane;

    f32x4 acc = (f32x4)0.f;

#pragma unroll
    for (int ck = 0; ck < 2; ++ck) {
        u64 regs[ROUNDS];
#pragma unroll
        for (int r = 0; r < ROUNDS; ++r) {
            int f = tid + r * 512;
            int row = f / U64PR;
            int kl = (f - row * U64PR) * 4;
            int gk = ck * (KTOT / 2) + kl;
            int grow = r0 + row;
            if constexpr (!LAY1) {
                if (gk < KX) {  // x part: static, L2-cached
                    regs[r] = *(const u64*)(x16 + ((size_t)grow * T_ + t) * KX + gk);
                } else {        // own h state = h1seqT[t]: fresh lines, nt cached load
                    regs[r] = __builtin_nontemporal_load(
                        (const u64*)(h1seqT + ((size_t)t * B_ + grow) * H_ + (gk - KX)));
                }
            } else {
                if (gk < KX) {  // h1seqT[t+1]: fresh lines, nt cached load
                    regs[r] = __builtin_nontemporal_load(
                        (const u64*)(h1seqT + ((size_t)(t + 1) * B_ + grow) * H_ + gk));
                } else {        // h2 ping-pong: reused addresses -> must bypass L2
                    regs[r] = sysld64(h2prev + (size_t)grow * H_ + (gk - KX));
                }
            }
        }
#pragma unroll
        for (int r = 0; r < ROUNDS; ++r) {
            int f = tid + r * 512;
            int row = f / U64PR;
            int kl = (f - row * U64PR) * 4;
            int byte = row * KTOT + kl * 2;      // row stride = KTOT/2 halves = KTOT bytes
            byte ^= (row & 7) << 4;
            *(u64*)(smA + byte) = regs[r];
        }
        __syncthreads();
        const int swz = (ml & 7) << 4;
#pragma unroll 8
        for (int kb = 0; kb < KBH; ++kb) {
            int byteA = ml * KTOT + kb * 64 + q * 16;
            half8 a = *(const half8*)(smA + (byteA ^ swz));
            half8 b = Wp8[wbase + (size_t)(ck * KBH + kb) * 128];
            acc = __builtin_amdgcn_mfma_f32_16x16x32_f16(a, b, acc, 0, 0, 0);
        }
        __syncthreads();
    }

    // acc -> gbuf : C/D layout col=lane&15, row=(lane>>4)*4+r (m89-verified)
#pragma unroll
    for (int r = 0; r < 4; ++r)
        gbuf[(q * 4 + r) * 128 + w * 16 + ml] = acc[r];
    __syncthreads();

    // elementwise: thread = (row, u) over 16 x 32 h-units
    {
        int row = tid >> 5, u = tid & 31;
        int hgl = u >> 3, hoff = u & 7;
        const float* gb = gbuf + row * 128 + hgl * 32 + hoff;
        float pi = gb[0], pf = gb[8], pg = gb[16], po = gb[24];
        const float* bb = biasp + (size_t)(cg * 4 + hgl) * 32 + hoff;
        pi += bb[0]; pf += bb[8]; pg += bb[16]; po += bb[24];
        int grow = r0 + row;
        int gunit = cg * 32 + u;
        size_t ci = (size_t)grow * H_ + gunit;
        float cold = cst[ci];
        float si = 1.f / (1.f + __expf(-pi));
        float sf = 1.f / (1.f + __expf(-pf));
        float so = 1.f / (1.f + __expf(-po));
        float tg = 1.f - 2.f / (__expf(2.f * pg) + 1.f);
        float cn = sf * cold + si * tg;
        float th = 1.f - 2.f / (__expf(2.f * cn) + 1.f);
        float hn = so * th;
        cst[ci] = cn;
        union { _Float16 hf; unsigned short us; } cvt;
        cvt.hf = (_Float16)hn;
        unsigned mine = cvt.us;
        unsigned other = (unsigned)__shfl_down((int)mine, 1, 64);
        if ((u & 1) == 0) {  // pack pair (u, u+1) -> one u32 system store
            unsigned pk = mine | ((other & 0xffffu) << 16);
            half_t* dst = LAY1 ? (h2next + ci)
                               : (h1seqT + ((size_t)(t + 1) * B_ + grow) * H_ + gunit);
            sysst32(dst, pk);
        }
    }
}

// ---------------------------------------------------------------------------
// Persistent: 512 blocks. bid<256: layer0 (writes h1seqT[t+1]); else layer1.
// bl = rg*32+cg  (same-cg blocks differ by 32 => co-XCD for L2 weight reuse).
// Sync: per-rg counters; L0 waits only on same-rg L0; L1 chases L0. Acyclic.
__launch_bounds__(512, 4)
__global__ void lstm_persist(const half_t* __restrict__ x16, half_t* h1seqT,
                             const half_t* __restrict__ wp0, const half_t* __restrict__ wp1,
                             const float* __restrict__ bias0, const float* __restrict__ bias1,
                             float* __restrict__ c0, float* __restrict__ c1,
                             half_t* h2a, half_t* h2b,
                             unsigned* __restrict__ ctrs)
{
    __shared__ char smA[32768];          // 16 rows x (KTOT/2<=1024) halves
    __shared__ float gbuf[16 * 128];     // 8 KB
    int bid = blockIdx.x;
    int lay = bid >> 8;
    int bl = bid & 255;
    int rg = bl >> 5, cg = bl & 31;
    unsigned* barL0 = ctrs + rg * 32;          // 128B-padded counters
    unsigned* barL1 = ctrs + 256 + rg * 32;

    if (lay == 0) {
        for (int t = 0; t < T_; ++t) {
            if (t > 0) wait_ge(barL0, 32u * (unsigned)t);     // h1seqT[t] complete
            lstm_step_p<1536, 512, false>(x16, h1seqT, (const half_t*)0, (half_t*)0,
                                          wp0, bias0, c0, t, rg, cg, smA, gbuf);
            signal(barL0);
        }
    } else {
        for (int t = 0; t < T_; ++t) {
            wait_ge(barL0, 32u * (unsigned)(t + 1));          // h1seqT[t+1] ready
            if (t > 0) wait_ge(barL1, 32u * (unsigned)t);     // h2[t-1] ready + WAR safe
            const half_t* hp = (t & 1) ? h2b : h2a;
            half_t* hn = (t & 1) ? h2a : h2b;
            lstm_step_p<2048, 1024, true>(x16, h1seqT, hp, hn,
                                          wp1, bias1, c1, t, rg, cg, smA, gbuf);
            signal(barL1);
        }
    }
}

// final FC: out[m] = sum_k h[m][k] * Wfc[k] + bfc  (NC=1)
__global__ void k_fc(const half_t* __restrict__ h, const float* __restrict__ Wfc,
                     const float* __restrict__ bfc, float* __restrict__ out) {
    int m = blockIdx.x, lane = threadIdx.x;
    float s = 0.f;
    for (int k = lane; k < H_; k += 64) s += (float)h[m * H_ + k] * Wfc[k];
#pragma unroll
    for (int o = 32; o; o >>= 1) s += __shfl_down(s, o, 64);
    if (lane == 0) out[m] = s + bfc[0];
}

// ---------------------------------------------------------------------------
extern "C" void kernel_launch(void* const* d_in, const int* in_sizes, int n_in,
                              void* d_out, int out_size, void* d_ws, size_t ws_size,
                              hipStream_t stream) {
    const float* x    = (const float*)d_in[0];
    const float* Wih0 = (const float*)d_in[1];
    const float* Whh0 = (const float*)d_in[2];
    const float* bih0 = (const float*)d_in[3];
    const float* bhh0 = (const float*)d_in[4];
    const float* Wih1 = (const float*)d_in[5];
    const float* Whh1 = (const float*)d_in[6];
    const float* bih1 = (const float*)d_in[7];
    const float* bhh1 = (const float*)d_in[8];
    const float* Wfc  = (const float*)d_in[9];
    const float* bfc  = (const float*)d_in[10];
    float* out = (float*)d_out;

    char* ws = (char*)d_ws;
    size_t off = 0;
    auto carve = [&](size_t bytes) { void* p = ws + off; off += (bytes + 255) & ~(size_t)255; return p; };
    half_t* x16    = (half_t*)carve((size_t)B_ * T_ * I_ * 2);              // 33.5 MB
    half_t* h1seqT = (half_t*)carve((size_t)(T_ + 1) * B_ * H_ * 2);        // 67.4 MB [t][row][unit]
    half_t* wp0    = (half_t*)carve((size_t)4096 * 1536 * 2);               // 12.6 MB
    half_t* wp1    = (half_t*)carve((size_t)4096 * 2048 * 2);               // 16.8 MB
    float*  bias0  = (float*)carve(4096 * 4);
    float*  bias1  = (float*)carve(4096 * 4);
    // states: h2a,h2b (fp16) + c0,c1 (fp32) + counters (2 KB)
    char*   states = (char*)carve(2 * (size_t)B_ * H_ * 2 + 2 * (size_t)B_ * H_ * 4 + 2048);
    if (off > ws_size) return;  // ws too small: visible failure

    half_t* h2a = (half_t*)states;
    half_t* h2b = h2a + B_ * H_;
    float*  c0  = (float*)(h2b + B_ * H_);
    float*  c1  = c0 + B_ * H_;
    unsigned* ctrs = (unsigned*)(c1 + B_ * H_);

    // prep
    k_convert_x<<<(B_ * T_ * I_ / 8 + 255) / 256, 256, 0, stream>>>(x, x16, B_ * T_ * I_ / 8);
    k_pack_w<<<(4096 * 1536 + 255) / 256, 256, 0, stream>>>(Wih0, Whh0, wp0, 512, 1536);
    k_pack_w<<<(4096 * 2048 + 255) / 256, 256, 0, stream>>>(Wih1, Whh1, wp1, 1024, 2048);
    k_pack_bias<<<16, 256, 0, stream>>>(bih0, bhh0, bias0);
    k_pack_bias<<<16, 256, 0, stream>>>(bih1, bhh1, bias1);
    // zero h1seqT slot 0 (initial h state for layer 0)
    k_zero<<<(B_ * H_ * 2 / 4 + 255) / 256, 256, 0, stream>>>((unsigned int*)h1seqT, B_ * H_ / 2);
    // zero h2a,h2b,c0,c1,counters — MUST happen every launch (bench replays!)
    {
        int n = (2 * B_ * H_ * 2 + 2 * B_ * H_ * 4 + 2048) / 4;
        k_zero<<<(n + 255) / 256, 256, 0, stream>>>((unsigned int*)states, n);
    }

    // persistent pipelined recurrence: one launch, fence-free sub-barriers
    lstm_persist<<<dim3(512), dim3(512), 0, stream>>>(
        x16, h1seqT, wp0, wp1, bias0, bias1, c0, c1, h2a, h2b, ctrs);

    // final h2 state after t=255 (odd) lives in h2a
    k_fc<<<128, 64, 0, stream>>>(h2a, Wfc, bfc, out);
}